// Round 5
// baseline (2372.371 us; speedup 1.0000x reference)
//
#include <hip/hip_runtime.h>
#include <stdint.h>

#define DMODEL 768
#define DINNER 1536
#define NSTATE 16
#define KCONV 4
#define RRANK 48
#define NLAYER 8
#define BLL 2048   // B*L tokens
#define LSEQ 1024
#define BATCH 2
#define NCHUNK 16
#define CLEN 64    // LSEQ / NCHUNK
#define DBLK 64
#define NDBLK (DINNER / DBLK)        // 24
#define NGROUPS (BATCH * NDBLK)      // 48
#define SCAN_GRID (NGROUPS * NCHUNK) // 768

#define GBM 128
#define GBN 128
#define GBK 32

__device__ __forceinline__ float bf2f(ushort u) {
  union { float f; uint32_t i; } v; v.i = ((uint32_t)u) << 16; return v.f;
}
__device__ __forceinline__ ushort f2bf(float f) {
  uint32_t x = __float_as_uint(f);
  uint32_t r = (x + 0x7fffu + ((x >> 16) & 1u)) >> 16;  // round-nearest-even
  return (ushort)r;
}
// flag-switched input loader: fp32flag=1 -> fp32 data, 0 -> bf16 data
__device__ __forceinline__ float ldf(const void* p, size_t i, int fp32flag) {
  return fp32flag ? ((const float*)p)[i] : bf2f(((const ushort*)p)[i]);
}

typedef __attribute__((ext_vector_type(8))) __bf16 bf16x8;
typedef __attribute__((ext_vector_type(4))) float f32x4;
typedef __attribute__((ext_vector_type(4))) unsigned short u16x4;

typedef __attribute__((address_space(3))) unsigned int lds_u32_t;
typedef const __attribute__((address_space(1))) unsigned int glb_u32_t;
// async global->LDS, 16B per lane; LDS dest = wave-uniform base + lane*16
__device__ __forceinline__ void gload16(const void* g, void* l) {
  __builtin_amdgcn_global_load_lds((glb_u32_t*)g, (lds_u32_t*)l, 16, 0, 0);
}

// ---------------- dtype probe: is input data fp32 or bf16? ----------------
__global__ __launch_bounds__(256) void probe_kernel(const void* emb, int* flag) {
  int tid = threadIdx.x;
  int good = 0;
  for (int i = tid; i < 4096; i += 256) {
    float v = bf2f(((const ushort*)emb)[2 * i]);  // little-endian low half
    float a = fabsf(v);
    if (v == 0.f || (a >= 1e-8f && a <= 1e4f)) good++;
  }
  __shared__ int red[4];
  #pragma unroll
  for (int off = 32; off > 0; off >>= 1) good += __shfl_down(good, off, 64);
  if ((tid & 63) == 0) red[tid >> 6] = good;
  __syncthreads();
  if (tid == 0) {
    int g = red[0] + red[1] + red[2] + red[3];
    *flag = (g < 2867) ? 1 : 0;   // <70% sane => fp32 inputs
  }
}

// ---------------- weight convert: input (either dtype) -> bf16 ws copy ----------------
__global__ __launch_bounds__(256) void wcvt_kernel(const void* src, size_t elem_off,
                                                   ushort* __restrict__ dst,
                                                   const int* __restrict__ flag) {
  int f = *flag;
  size_t i = (size_t)blockIdx.x * 256 + threadIdx.x;
  dst[i] = f2bf(ldf(src, elem_off + i, f));
}

// ---------------- dt_proj_w pad+convert: [l][d][48] -> [l][d][64] bf16 ----------------
__global__ __launch_bounds__(256) void dtwpad_kernel(const void* dtw, ushort* __restrict__ dst,
                                                     const int* __restrict__ flag) {
  int f = *flag;
  size_t i = (size_t)blockIdx.x * 256 + threadIdx.x;   // NLAYER*DINNER*64
  int r = i & 63;
  size_t dl = i >> 6;                                  // l*DINNER + d
  dst[i] = (r < RRANK) ? f2bf(ldf(dtw, dl * RRANK + r, f)) : (ushort)0;
}

// ---------------- embedding lookup -> fp32 residual ----------------
__global__ __launch_bounds__(256) void embed_kernel(
    const int* __restrict__ ids, const void* __restrict__ emb,
    float* __restrict__ res, const int* __restrict__ flag) {
  int f = *flag;
  int idx = blockIdx.x * 256 + threadIdx.x;           // BLL*DMODEL
  int m = idx / DMODEL, c = idx % DMODEL;
  res[idx] = ldf(emb, (size_t)ids[m] * DMODEL + c, f);
}

// ---------------- RMSNorm: res(f32) -> h(bf16) or final out (per flag) ----------------
__global__ __launch_bounds__(256) void rms_kernel(
    const float* __restrict__ res, const void* __restrict__ w, size_t w_off,
    void* __restrict__ out, const int* __restrict__ flag, int final_store) {
  int f = *flag;
  int m = blockIdx.x;
  const float* r = res + (size_t)m * DMODEL;
  float ss = 0.f;
  for (int i = threadIdx.x; i < DMODEL; i += 256) { float v = r[i]; ss += v * v; }
  #pragma unroll
  for (int off = 32; off > 0; off >>= 1) ss += __shfl_down(ss, off, 64);
  __shared__ float red[4];
  if ((threadIdx.x & 63) == 0) red[threadIdx.x >> 6] = ss;
  __syncthreads();
  float scale = rsqrtf((red[0] + red[1] + red[2] + red[3]) / (float)DMODEL + 1e-5f);
  for (int i = threadIdx.x; i < DMODEL; i += 256) {
    float v = r[i] * scale * ldf(w, w_off + i, f);
    size_t o = (size_t)m * DMODEL + i;
    if (final_store) {
      if (f) ((float*)out)[o] = v; else ((ushort*)out)[o] = f2bf(v);
    } else {
      ((ushort*)out)[o] = f2bf(v);
    }
  }
}

// ---------------- x_proj GEMM (N=80): C = A*W^T; bn==0 block also emits bf16 dt_raw[.,0:64] ----------------
__global__ __launch_bounds__(256) void gemm_xproj(
    const ushort* __restrict__ A, const ushort* __restrict__ W,
    float* __restrict__ Cout, ushort* __restrict__ dtraw, int M, int N, int K) {
  int wave = threadIdx.x >> 6, lane = threadIdx.x & 63;
  int quad = lane >> 4, lq = lane & 15;
  int bm = blockIdx.y * 64, bn = blockIdx.x * 64;
  int row = bm + wave * 16 + lq;
  const ushort* Ap = A + (size_t)row * K + quad * 8;
  f32x4 acc[4] = {};
  for (int kk = 0; kk < K; kk += 32) {
    bf16x8 af = *(const bf16x8*)(Ap + kk);
    #pragma unroll
    for (int t = 0; t < 4; ++t) {
      int col = bn + t * 16 + lq;
      bf16x8 bfv = {};
      if (col < N) bfv = *(const bf16x8*)(W + (size_t)col * K + kk + quad * 8);
      acc[t] = __builtin_amdgcn_mfma_f32_16x16x32_bf16(af, bfv, acc[t], 0, 0, 0);
    }
  }
  #pragma unroll
  for (int t = 0; t < 4; ++t) {
    int col = bn + t * 16 + lq;
    #pragma unroll
    for (int r = 0; r < 4; ++r) {
      int rr = bm + wave * 16 + quad * 4 + r;
      if (col < N) Cout[(size_t)rr * N + col] = acc[t][r];
      if (bn == 0)   // cols 0..63 = padded dt_raw block
        dtraw[(size_t)rr * 64 + col] = (col < RRANK) ? f2bf(acc[t][r]) : (ushort)0;
    }
  }
}

// ---------------- 128x128 LDS-staged MFMA GEMM (m97 structure) ----------------
// OUT_MODE: 0 = f32 store, 2 = f32 atomic-accumulate (split-K safe),
//           3 = softplus(acc + bias) store (dt projection).
// LDS tiles [128][32] bf16, linear dest for global_load_lds; bank-conflict fix via
// both-sides XOR swizzle: 16B-chunk index ^= (row>>1)&3 (involution; rule 21).
template <int OUT_MODE>
__global__ __launch_bounds__(256) void gemm128(
    const ushort* __restrict__ A, const ushort* __restrict__ W,
    float* __restrict__ Cout, int M, int N, int K, int ksplit,
    const void* bias, size_t bias_off, const int* __restrict__ flagp) {
  __shared__ __align__(16) ushort As[2][GBM * GBK];   // 8 KB each
  __shared__ __align__(16) ushort Bs[2][GBM * GBK];
  const int tid = threadIdx.x;
  const int wid = tid >> 6, lane = tid & 63;
  const int quad = lane >> 4, lq = lane & 15;
  const int wm = wid >> 1, wn = wid & 1;              // 2x2 waves, 64x64 each
  const int bm = blockIdx.y * GBM, bn = blockIdx.x * GBN;
  const int kslice = K / ksplit;
  const int kbase = blockIdx.z * kslice;

  // staging: 512 chunks of 16B per tile; chunk i -> LDS offset i*16 (linear).
  // physical chunk (row, pc) holds logical k-octet lc = pc ^ ((row>>1)&3).
  const int c0 = tid, c1 = tid + 256;
  const int r0 = c0 >> 2, lc0 = (c0 & 3) ^ ((r0 >> 1) & 3);
  const int r1 = c1 >> 2, lc1 = (c1 & 3) ^ ((r1 >> 1) & 3);
  const ushort* Ag0 = A + (size_t)(bm + r0) * K + kbase + lc0 * 8;
  const ushort* Ag1 = A + (size_t)(bm + r1) * K + kbase + lc1 * 8;
  const ushort* Bg0 = W + (size_t)(bn + r0) * K + kbase + lc0 * 8;
  const ushort* Bg1 = W + (size_t)(bn + r1) * K + kbase + lc1 * 8;
  const int ls0 = wid * 512;                          // elem offsets (wave-uniform)
  const int ls1 = 2048 + wid * 512;

  // per-lane ds_read byte offsets (swizzled)
  int offA[4], offB[4];
  #pragma unroll
  for (int m = 0; m < 4; ++m) {
    int ra = wm * 64 + m * 16 + lq;
    offA[m] = ra * 64 + ((quad ^ ((ra >> 1) & 3)) << 4);
    int rb = wn * 64 + m * 16 + lq;
    offB[m] = rb * 64 + ((quad ^ ((rb >> 1) & 3)) << 4);
  }

  f32x4 acc[4][4] = {};
  const int nk = kslice >> 5;

  gload16(Ag0, &As[0][ls0]); gload16(Ag1, &As[0][ls1]);
  gload16(Bg0, &Bs[0][ls0]); gload16(Bg1, &Bs[0][ls1]);
  __syncthreads();

  int buf = 0;
  for (int kk = 1; kk < nk; ++kk) {
    const int ko = kk << 5;
    gload16(Ag0 + ko, &As[buf ^ 1][ls0]); gload16(Ag1 + ko, &As[buf ^ 1][ls1]);
    gload16(Bg0 + ko, &Bs[buf ^ 1][ls0]); gload16(Bg1 + ko, &Bs[buf ^ 1][ls1]);
    bf16x8 af[4], bfv[4];
    #pragma unroll
    for (int m = 0; m < 4; ++m) af[m] = *(const bf16x8*)((const char*)As[buf] + offA[m]);
    #pragma unroll
    for (int n = 0; n < 4; ++n) bfv[n] = *(const bf16x8*)((const char*)Bs[buf] + offB[n]);
    #pragma unroll
    for (int m = 0; m < 4; ++m)
      #pragma unroll
      for (int n = 0; n < 4; ++n)
        acc[m][n] = __builtin_amdgcn_mfma_f32_16x16x32_bf16(af[m], bfv[n], acc[m][n], 0, 0, 0);
    __syncthreads();
    buf ^= 1;
  }
  {
    bf16x8 af[4], bfv[4];
    #pragma unroll
    for (int m = 0; m < 4; ++m) af[m] = *(const bf16x8*)((const char*)As[buf] + offA[m]);
    #pragma unroll
    for (int n = 0; n < 4; ++n) bfv[n] = *(const bf16x8*)((const char*)Bs[buf] + offB[n]);
    #pragma unroll
    for (int m = 0; m < 4; ++m)
      #pragma unroll
      for (int n = 0; n < 4; ++n)
        acc[m][n] = __builtin_amdgcn_mfma_f32_16x16x32_bf16(af[m], bfv[n], acc[m][n], 0, 0, 0);
  }

  const int f = (OUT_MODE == 3) ? *flagp : 0;
  #pragma unroll
  for (int n = 0; n < 4; ++n) {
    int col = bn + wn * 64 + n * 16 + lq;
    #pragma unroll
    for (int m = 0; m < 4; ++m) {
      #pragma unroll
      for (int r = 0; r < 4; ++r) {
        int row = bm + wm * 64 + m * 16 + quad * 4 + r;
        size_t off = (size_t)row * N + col;
        if (OUT_MODE == 0) {
          Cout[off] = acc[m][n][r];
        } else if (OUT_MODE == 2) {
          atomicAdd(&Cout[off], acc[m][n][r]);
        } else {  // 3: dt = softplus(acc + bias[col])
          float s = acc[m][n][r] + ldf(bias, bias_off + col, f);
          Cout[off] = (s > 20.f) ? s : log1pf(__expf(s));
        }
      }
    }
  }
}

// ---------------- causal depthwise conv (K=4) + SiLU ----------------
__global__ __launch_bounds__(256) void conv_kernel(
    const float* __restrict__ xz, const void* __restrict__ cw, size_t cw_off,
    const void* __restrict__ cb, size_t cb_off,
    ushort* __restrict__ xcb, float* __restrict__ xcf,
    const int* __restrict__ flag) {
  int f = *flag;
  int idx = blockIdx.x * 256 + threadIdx.x;           // BLL*DINNER
  int d = idx % DINNER, m = idx / DINNER;
  int l = m & (LSEQ - 1);
  float s = ldf(cb, cb_off + d, f);
  #pragma unroll
  for (int k = 0; k < KCONV; ++k) {
    int ls = l - (KCONV - 1) + k;
    if (ls >= 0)
      s = fmaf(xz[(size_t)(m - (KCONV - 1) + k) * (2 * DINNER) + d],
               ldf(cw, cw_off + d * KCONV + k, f), s);
  }
  float v = s / (1.f + __expf(-s));   // silu
  xcb[idx] = f2bf(v);
  xcf[idx] = v;
}

// ============ chunk-parallel selective scan, 3-phase (no cross-block sync) ============
// blockIdx = grp*NCHUNK + chunk; grp = b*NDBLK + dblk.
// Thread map: dloc = tid>>2 (one of 64 d), ngrp = tid&3 (4 n-states in registers).
// LDS stages via global_load_lds (linear lane-ordered layouts; wave-uniform base + lane*16).

// P1: chunk-local scan from 0. P computed as exp(sum(dt)*A) — one exp per state.
__global__ __launch_bounds__(256) void scan_p1(
    const float* __restrict__ dt, const float* __restrict__ xcf,
    const float* __restrict__ dbl,
    const void* __restrict__ A_log, size_t al_off,
    float* __restrict__ carryP, float* __restrict__ carryH,
    const int* __restrict__ flag) {
  __shared__ __align__(16) float dt_s[CLEN * DBLK];   // 16 KB
  __shared__ __align__(16) float u_s[CLEN * DBLK];    // 16 KB
  __shared__ __align__(16) f32x4 B4_s[CLEN][4];       // 4 KB

  const int f = *flag;
  const int tid = threadIdx.x;
  const int bid = blockIdx.x;
  const int chunk = bid & (NCHUNK - 1);
  const int grp = bid >> 4;
  const int dblk = grp % NDBLK;
  const int b = grp / NDBLK;
  const int l0 = chunk * CLEN;
  const int dloc = tid >> 2;
  const int ngrp = tid & 3;
  const int d = dblk * DBLK + dloc;

  #pragma unroll
  for (int t = tid; t < CLEN * DBLK / 4; t += 256) {
    int l = t >> 4, c = t & 15;
    size_t off = ((size_t)b * LSEQ + l0 + l) * DINNER + dblk * DBLK + c * 4;
    gload16(dt + off,  (char*)dt_s + (size_t)t * 16);
    gload16(xcf + off, (char*)u_s  + (size_t)t * 16);
  }
  {
    size_t mo = ((size_t)b * LSEQ + l0 + (tid >> 2)) * 80;
    gload16(dbl + mo + 48 + (tid & 3) * 4, (char*)B4_s + (size_t)tid * 16);
  }

  float Ac[4];
  #pragma unroll
  for (int j = 0; j < 4; ++j)
    Ac[j] = -__expf(ldf(A_log, al_off + (size_t)d * NSTATE + ngrp * 4 + j, f));

  __syncthreads();

  float h[4] = {0.f, 0.f, 0.f, 0.f};
  float sdt = 0.f;
  #pragma unroll 4
  for (int l = 0; l < CLEN; ++l) {
    float dtv = dt_s[l * DBLK + dloc], uu = u_s[l * DBLK + dloc];
    f32x4 Bv = B4_s[l][ngrp];
    float dtu = dtv * uu;
    sdt += dtv;
    #pragma unroll
    for (int j = 0; j < 4; ++j) {
      float a = __expf(dtv * Ac[j]);
      h[j] = fmaf(a, h[j], dtu * Bv[j]);
    }
  }
  size_t cb = ((size_t)bid * DBLK + dloc) * NSTATE + ngrp * 4;
  #pragma unroll
  for (int j = 0; j < 4; ++j) {
    carryP[cb + j] = __expf(sdt * Ac[j]);
    carryH[cb + j] = h[j];
  }
}

// P2: sequential carry combine over chunks; coalesced within each group.
__global__ __launch_bounds__(256) void scan_p2(
    const float* __restrict__ carryP, const float* __restrict__ carryH,
    float* __restrict__ hin) {
  int idx = blockIdx.x * 256 + threadIdx.x;          // NGROUPS*DBLK*NSTATE = 49152
  int n = idx & 15;
  int dloc = (idx >> 4) & (DBLK - 1);
  int grp = idx >> 10;
  float h = 0.f;
  for (int c = 0; c < NCHUNK; ++c) {
    size_t ci = (((size_t)(grp * NCHUNK + c)) * DBLK + dloc) * NSTATE + n;
    hin[ci] = h;
    h = fmaf(carryP[ci], h, carryH[ci]);
  }
}

// P3: true recurrence from hin; in-register n-partials, 4-lane reduce,
//     fused D-skip + silu(z) gate, vectorized coalesced bf16 store.
__global__ __launch_bounds__(256) void scan_p3(
    const float* __restrict__ dt, const float* __restrict__ xcf,
    const float* __restrict__ dbl, const float* __restrict__ xz,
    const void* __restrict__ A_log, size_t al_off,
    const void* __restrict__ Dp, size_t dp_off,
    const float* __restrict__ hin, ushort* __restrict__ yg,
    const int* __restrict__ flag) {
  __shared__ __align__(16) float dt_s[CLEN * DBLK];   // 16 KB
  __shared__ __align__(16) float u_s[CLEN * DBLK];    // 16 KB
  __shared__ __align__(16) f32x4 B4_s[CLEN][4];       // 4 KB
  __shared__ __align__(16) f32x4 C4_s[CLEN][4];       // 4 KB
  __shared__ ushort ybuf[CLEN][DBLK];                 // 8 KB  => 48 KB total

  const int f = *flag;
  const int tid = threadIdx.x;
  const int bid = blockIdx.x;
  const int chunk = bid & (NCHUNK - 1);
  const int grp = bid >> 4;
  const int dblk = grp % NDBLK;
  const int b = grp / NDBLK;
  const int l0 = chunk * CLEN;
  const int dloc = tid >> 2;
  const int ngrp = tid & 3;
  const int d = dblk * DBLK + dloc;

  #pragma unroll
  for (int t = tid; t < CLEN * DBLK / 4; t += 256) {
    int l = t >> 4, c = t & 15;
    size_t off = ((size_t)b * LSEQ + l0 + l) * DINNER + dblk * DBLK + c * 4;
    gload16(dt + off,  (char*)dt_s + (size_t)t * 16);
    gload16(xcf + off, (char*)u_s  + (size_t)t * 16);
  }
  {
    size_t mo = ((size_t)b * LSEQ + l0 + (tid >> 2)) * 80;
    gload16(dbl + mo + 48 + (tid & 3) * 4, (char*)B4_s + (size_t)tid * 16);
    gload16(dbl + mo + 64 + (tid & 3) * 4, (char*)C4_s + (size_t)tid * 16);
  }

  float Ac[4];
  #pragma unroll
  for (int j = 0; j < 4; ++j)
    Ac[j] = -__expf(ldf(A_log, al_off + (size_t)d * NSTATE + ngrp * 4 + j, f));
  const float Dd = ldf(Dp, dp_off + d, f);

  size_t hb = ((size_t)bid * DBLK + dloc) * NSTATE + ngrp * 4;
  float hp[4] = {hin[hb], hin[hb + 1], hin[hb + 2], hin[hb + 3]};

  __syncthreads();

  #pragma unroll 4
  for (int l = 0; l < CLEN; ++l) {
    float dtv = dt_s[l * DBLK + dloc], uu = u_s[l * DBLK + dloc];
    f32x4 Bv = B4_s[l][ngrp];
    f32x4 Cv = C4_s[l][ngrp];
    float dtu = dtv * uu;
    float yp = 0.f;
    #pragma unroll
    for (int j = 0; j < 4; ++j) {
      float a = __expf(dtv * Ac[j]);
      hp[j] = fmaf(a, hp[j], dtu * Bv[j]);
      yp = fmaf(hp[j], Cv[j], yp);
    }
    yp += __shfl_xor(yp, 1, 64);
    yp += __shfl_xor(yp, 2, 64);
    if (ngrp == 0) ybuf[l][dloc] = f2bf(yp + uu * Dd);
  }
  __syncthreads();

  // ---- gated write: y * silu(z), coalesced vectorized ----
  #pragma unroll
  for (int t = tid; t < CLEN * DBLK / 4; t += 256) {
    int l = t >> 4, c = t & 15;
    size_t m = (size_t)b * LSEQ + l0 + l;
    f32x4 z4 = *(const f32x4*)(xz + m * (2 * DINNER) + DINNER + dblk * DBLK + c * 4);
    u16x4 o;
    #pragma unroll
    for (int j = 0; j < 4; ++j) {
      float y = bf2f(ybuf[l][c * 4 + j]);
      float zv = z4[j];
      float g = zv / (1.f + __expf(-zv));
      o[j] = f2bf(y * g);
    }
    *(u16x4*)(yg + m * DINNER + dblk * DBLK + c * 4) = o;
  }
}

extern "C" void kernel_launch(void* const* d_in, const int* in_sizes, int n_in,
                              void* d_out, int out_size, void* d_ws, size_t ws_size,
                              hipStream_t stream) {
  const int*  ids   = (const int*)d_in[0];
  const void* emb   = d_in[1];
  const void* inw   = d_in[2];
  const void* cw    = d_in[3];
  const void* cb    = d_in[4];
  const void* xpw   = d_in[5];
  const void* dtw   = d_in[6];
  const void* dtb   = d_in[7];
  const void* alog  = d_in[8];
  const void* dpar  = d_in[9];
  const void* outw  = d_in[10];
  const void* normw = d_in[11];
  const void* normf = d_in[12];

  // workspace layout, all chunks 16B-aligned
  char* p = (char*)d_ws;
  int*    flag = (int*)p;    p += 16;
  float*  res  = (float*)p;  p += (size_t)BLL * DMODEL * 4;
  ushort* h    = (ushort*)p; p += (size_t)BLL * DMODEL * 2;
  float*  xz   = (float*)p;  p += (size_t)BLL * 2 * DINNER * 4;
  ushort* xcb  = (ushort*)p; p += (size_t)BLL * DINNER * 2;
  float*  xcf  = (float*)p;  p += (size_t)BLL * DINNER * 4;
  float*  dbl  = (float*)p;  p += (size_t)BLL * 80 * 4;
  float*  dt   = (float*)p;  p += (size_t)BLL * DINNER * 4;
  ushort* yg   = (ushort*)p; p += (size_t)BLL * DINNER * 2;
  float*  carryP = (float*)p; p += (size_t)SCAN_GRID * DBLK * NSTATE * 4;
  float*  carryH = (float*)p; p += (size_t)SCAN_GRID * DBLK * NSTATE * 4;
  float*  hin    = (float*)p; p += (size_t)SCAN_GRID * DBLK * NSTATE * 4;
  ushort* dtrawb = (ushort*)p; p += (size_t)BLL * 64 * 2;
  ushort* dtwpb  = (ushort*)p; p += (size_t)NLAYER * DINNER * 64 * 2;
  ushort* inwb = (ushort*)p; p += (size_t)NLAYER * 2 * DINNER * DMODEL * 2;
  ushort* xpwb = (ushort*)p; p += (size_t)NLAYER * 80 * DINNER * 2;
  ushort* outwb= (ushort*)p; p += (size_t)NLAYER * DMODEL * DINNER * 2;

  probe_kernel<<<1, 256, 0, stream>>>(emb, flag);
  wcvt_kernel<<<(NLAYER * 2 * DINNER * DMODEL) / 256, 256, 0, stream>>>(inw, 0, inwb, flag);
  wcvt_kernel<<<(NLAYER * 80 * DINNER) / 256, 256, 0, stream>>>(xpw, 0, xpwb, flag);
  wcvt_kernel<<<(NLAYER * DMODEL * DINNER) / 256, 256, 0, stream>>>(outw, 0, outwb, flag);
  dtwpad_kernel<<<(NLAYER * DINNER * 64) / 256, 256, 0, stream>>>(dtw, dtwpb, flag);

  embed_kernel<<<BLL * DMODEL / 256, 256, 0, stream>>>(ids, emb, res, flag);

  for (int i = 0; i < NLAYER; ++i) {
    rms_kernel<<<BLL, 256, 0, stream>>>(res, normw, (size_t)i * DMODEL, h, flag, 0);
    gemm128<0><<<dim3(2 * DINNER / GBN, BLL / GBM), 256, 0, stream>>>(
        h, inwb + (size_t)i * 2 * DINNER * DMODEL, xz, BLL, 2 * DINNER, DMODEL, 1,
        nullptr, 0, nullptr);
    conv_kernel<<<BLL * DINNER / 256, 256, 0, stream>>>(
        xz, cw, (size_t)i * DINNER * KCONV, cb, (size_t)i * DINNER, xcb, xcf, flag);
    gemm_xproj<<<dim3(2, BLL / 64), 256, 0, stream>>>(
        xcb, xpwb + (size_t)i * 80 * DINNER, dbl, dtrawb, BLL, 80, DINNER);
    gemm128<3><<<dim3(DINNER / GBN, BLL / GBM), 256, 0, stream>>>(
        dtrawb, dtwpb + (size_t)i * DINNER * 64, dt, BLL, DINNER, 64, 1,
        dtb, (size_t)i * DINNER, flag);
    scan_p1<<<SCAN_GRID, 256, 0, stream>>>(
        dt, xcf, dbl, alog, (size_t)i * DINNER * NSTATE, carryP, carryH, flag);
    scan_p2<<<NGROUPS * DBLK * NSTATE / 256, 256, 0, stream>>>(carryP, carryH, hin);
    scan_p3<<<SCAN_GRID, 256, 0, stream>>>(
        dt, xcf, dbl, xz, alog, (size_t)i * DINNER * NSTATE, dpar, (size_t)i * DINNER,
        hin, yg, flag);
    gemm128<2><<<dim3(DMODEL / GBN, BLL / GBM, 4), 256, 0, stream>>>(
        yg, outwb + (size_t)i * DMODEL * DINNER, res, BLL, DMODEL, DINNER, 4,
        nullptr, 0, nullptr);
  }

  rms_kernel<<<BLL, 256, 0, stream>>>(res, normf, 0, d_out, flag, 1);
}

// Round 6
// 2152.922 us; speedup vs baseline: 1.1019x; 1.1019x over previous
//
#include <hip/hip_runtime.h>
#include <stdint.h>

#define DMODEL 768
#define DINNER 1536
#define NSTATE 16
#define KCONV 4
#define RRANK 48
#define NLAYER 8
#define BLL 2048   // B*L tokens
#define LSEQ 1024
#define BATCH 2
#define NCHUNK 16
#define CLEN 64    // LSEQ / NCHUNK
#define DBLK 64
#define NDBLK (DINNER / DBLK)        // 24
#define NGROUPS (BATCH * NDBLK)      // 48
#define SCAN_GRID (NGROUPS * NCHUNK) // 768

#define GBM 128
#define GBN 128
#define GBK 32

__device__ __forceinline__ float bf2f(ushort u) {
  union { float f; uint32_t i; } v; v.i = ((uint32_t)u) << 16; return v.f;
}
__device__ __forceinline__ ushort f2bf(float f) {
  uint32_t x = __float_as_uint(f);
  uint32_t r = (x + 0x7fffu + ((x >> 16) & 1u)) >> 16;  // round-nearest-even
  return (ushort)r;
}
// flag-switched input loader: fp32flag=1 -> fp32 data, 0 -> bf16 data
__device__ __forceinline__ float ldf(const void* p, size_t i, int fp32flag) {
  return fp32flag ? ((const float*)p)[i] : bf2f(((const ushort*)p)[i]);
}

typedef __attribute__((ext_vector_type(8))) __bf16 bf16x8;
typedef __attribute__((ext_vector_type(4))) float f32x4;
typedef __attribute__((ext_vector_type(4))) unsigned short u16x4;

typedef __attribute__((address_space(3))) unsigned int lds_u32_t;
typedef const __attribute__((address_space(1))) unsigned int glb_u32_t;
// async global->LDS, 16B per lane; LDS dest = wave-uniform base + lane*16
__device__ __forceinline__ void gload16(const void* g, void* l) {
  __builtin_amdgcn_global_load_lds((glb_u32_t*)g, (lds_u32_t*)l, 16, 0, 0);
}

// ---------------- dtype probe: is input data fp32 or bf16? ----------------
__global__ __launch_bounds__(256) void probe_kernel(const void* emb, int* flag) {
  int tid = threadIdx.x;
  int good = 0;
  for (int i = tid; i < 4096; i += 256) {
    float v = bf2f(((const ushort*)emb)[2 * i]);  // little-endian low half
    float a = fabsf(v);
    if (v == 0.f || (a >= 1e-8f && a <= 1e4f)) good++;
  }
  __shared__ int red[4];
  #pragma unroll
  for (int off = 32; off > 0; off >>= 1) good += __shfl_down(good, off, 64);
  if ((tid & 63) == 0) red[tid >> 6] = good;
  __syncthreads();
  if (tid == 0) {
    int g = red[0] + red[1] + red[2] + red[3];
    *flag = (g < 2867) ? 1 : 0;   // <70% sane => fp32 inputs
  }
}

// ---------------- weight convert: input (either dtype) -> bf16 ws copy ----------------
__global__ __launch_bounds__(256) void wcvt_kernel(const void* src, size_t elem_off,
                                                   ushort* __restrict__ dst,
                                                   const int* __restrict__ flag) {
  int f = *flag;
  size_t i = (size_t)blockIdx.x * 256 + threadIdx.x;
  dst[i] = f2bf(ldf(src, elem_off + i, f));
}

// ---------------- dt_proj_w transpose: [l][d][r] -> [l][r][d], fp32 ----------------
__global__ __launch_bounds__(256) void dtwT_kernel(const void* dtw, float* __restrict__ dtwT,
                                                   const int* __restrict__ flag) {
  int f = *flag;
  size_t i = (size_t)blockIdx.x * 256 + threadIdx.x;   // NLAYER*RRANK*DINNER
  int d = i % DINNER;
  int r = (i / DINNER) % RRANK;
  int l = i / (DINNER * RRANK);
  dtwT[i] = ldf(dtw, ((size_t)l * DINNER + d) * RRANK + r, f);
}

// ---------------- embedding lookup -> fp32 residual ----------------
__global__ __launch_bounds__(256) void embed_kernel(
    const int* __restrict__ ids, const void* __restrict__ emb,
    float* __restrict__ res, const int* __restrict__ flag) {
  int f = *flag;
  int idx = blockIdx.x * 256 + threadIdx.x;           // BLL*DMODEL
  int m = idx / DMODEL, c = idx % DMODEL;
  res[idx] = ldf(emb, (size_t)ids[m] * DMODEL + c, f);
}

// ---------------- RMSNorm: res(f32) -> h(bf16) or final out (per flag) ----------------
__global__ __launch_bounds__(256) void rms_kernel(
    const float* __restrict__ res, const void* __restrict__ w, size_t w_off,
    void* __restrict__ out, const int* __restrict__ flag, int final_store) {
  int f = *flag;
  int m = blockIdx.x;
  const float* r = res + (size_t)m * DMODEL;
  float ss = 0.f;
  for (int i = threadIdx.x; i < DMODEL; i += 256) { float v = r[i]; ss += v * v; }
  #pragma unroll
  for (int off = 32; off > 0; off >>= 1) ss += __shfl_down(ss, off, 64);
  __shared__ float red[4];
  if ((threadIdx.x & 63) == 0) red[threadIdx.x >> 6] = ss;
  __syncthreads();
  float scale = rsqrtf((red[0] + red[1] + red[2] + red[3]) / (float)DMODEL + 1e-5f);
  for (int i = threadIdx.x; i < DMODEL; i += 256) {
    float v = r[i] * scale * ldf(w, w_off + i, f);
    size_t o = (size_t)m * DMODEL + i;
    if (final_store) {
      if (f) ((float*)out)[o] = v; else ((ushort*)out)[o] = f2bf(v);
    } else {
      ((ushort*)out)[o] = f2bf(v);
    }
  }
}

// ---------------- small GEMM (N not mult of 64): C[M,N] = A[M,K]*W[N,K]^T ----------------
template <int OUT_MODE>  // 0 = f32 store, 2 = f32 accumulate
__global__ __launch_bounds__(256) void gemm_nt(
    const ushort* __restrict__ A, const ushort* __restrict__ W,
    float* __restrict__ Cout, int M, int N, int K) {
  int wave = threadIdx.x >> 6, lane = threadIdx.x & 63;
  int quad = lane >> 4, lq = lane & 15;
  int bm = blockIdx.y * 64, bn = blockIdx.x * 64;
  int row = bm + wave * 16 + lq;
  const ushort* Ap = A + (size_t)row * K + quad * 8;
  f32x4 acc[4] = {};
  for (int kk = 0; kk < K; kk += 32) {
    bf16x8 af = *(const bf16x8*)(Ap + kk);
    #pragma unroll
    for (int t = 0; t < 4; ++t) {
      int col = bn + t * 16 + lq;
      bf16x8 bfv = {};
      if (col < N) bfv = *(const bf16x8*)(W + (size_t)col * K + kk + quad * 8);
      acc[t] = __builtin_amdgcn_mfma_f32_16x16x32_bf16(af, bfv, acc[t], 0, 0, 0);
    }
  }
  #pragma unroll
  for (int t = 0; t < 4; ++t) {
    int col = bn + t * 16 + lq;
    if (col >= N) continue;
    #pragma unroll
    for (int r = 0; r < 4; ++r) {
      int rr = bm + wave * 16 + quad * 4 + r;
      size_t off = (size_t)rr * N + col;
      if (OUT_MODE == 0) Cout[off] = acc[t][r];
      else               Cout[off] += acc[t][r];
    }
  }
}

// ---------------- 128x128 LDS-staged MFMA GEMM (m97 structure) ----------------
// Requires M%128==0, N%128==0, K%32==0, grid-total %8==0 (XCD swizzle).
// LDS tiles [128][32] bf16, linear dest for global_load_lds; bank-conflict fix via
// both-sides XOR swizzle: 16B-chunk index ^= (row>>1)&3 (involution; rule 21).
// T1: XCD-aware block swizzle (bijective since nwg%8==0 at both call sites).
template <int OUT_MODE>  // 0 = f32 store, 2 = f32 accumulate
__global__ __launch_bounds__(256) void gemm128(
    const ushort* __restrict__ A, const ushort* __restrict__ W,
    float* __restrict__ Cout, int M, int N, int K) {
  __shared__ __align__(16) ushort As[2][GBM * GBK];   // 8 KB each
  __shared__ __align__(16) ushort Bs[2][GBM * GBK];
  const int tid = threadIdx.x;
  const int wid = tid >> 6, lane = tid & 63;
  const int quad = lane >> 4, lq = lane & 15;
  const int wm = wid >> 1, wn = wid & 1;              // 2x2 waves, 64x64 each

  // XCD-aware bijective swizzle of the flattened block index
  const int nwg = gridDim.x * gridDim.y;
  const int orig = blockIdx.y * gridDim.x + blockIdx.x;
  const int swz = (orig & 7) * (nwg >> 3) + (orig >> 3);
  const int bx = swz % gridDim.x, by = swz / gridDim.x;
  const int bm = by * GBM, bn = bx * GBN;

  // staging: 512 chunks of 16B per tile; chunk i -> LDS offset i*16 (linear).
  // physical chunk (row, pc) holds logical k-octet lc = pc ^ ((row>>1)&3).
  const int c0 = tid, c1 = tid + 256;
  const int r0 = c0 >> 2, lc0 = (c0 & 3) ^ ((r0 >> 1) & 3);
  const int r1 = c1 >> 2, lc1 = (c1 & 3) ^ ((r1 >> 1) & 3);
  const ushort* Ag0 = A + (size_t)(bm + r0) * K + lc0 * 8;
  const ushort* Ag1 = A + (size_t)(bm + r1) * K + lc1 * 8;
  const ushort* Bg0 = W + (size_t)(bn + r0) * K + lc0 * 8;
  const ushort* Bg1 = W + (size_t)(bn + r1) * K + lc1 * 8;
  const int ls0 = wid * 512;                          // elem offsets (wave-uniform)
  const int ls1 = 2048 + wid * 512;

  // per-lane ds_read byte offsets (swizzled)
  int offA[4], offB[4];
  #pragma unroll
  for (int m = 0; m < 4; ++m) {
    int ra = wm * 64 + m * 16 + lq;
    offA[m] = ra * 64 + ((quad ^ ((ra >> 1) & 3)) << 4);
    int rb = wn * 64 + m * 16 + lq;
    offB[m] = rb * 64 + ((quad ^ ((rb >> 1) & 3)) << 4);
  }

  f32x4 acc[4][4] = {};
  const int nk = K >> 5;

  gload16(Ag0, &As[0][ls0]); gload16(Ag1, &As[0][ls1]);
  gload16(Bg0, &Bs[0][ls0]); gload16(Bg1, &Bs[0][ls1]);
  __syncthreads();

  int buf = 0;
  for (int kk = 1; kk < nk; ++kk) {
    const int ko = kk << 5;
    gload16(Ag0 + ko, &As[buf ^ 1][ls0]); gload16(Ag1 + ko, &As[buf ^ 1][ls1]);
    gload16(Bg0 + ko, &Bs[buf ^ 1][ls0]); gload16(Bg1 + ko, &Bs[buf ^ 1][ls1]);
    bf16x8 af[4], bfv[4];
    #pragma unroll
    for (int m = 0; m < 4; ++m) af[m] = *(const bf16x8*)((const char*)As[buf] + offA[m]);
    #pragma unroll
    for (int n = 0; n < 4; ++n) bfv[n] = *(const bf16x8*)((const char*)Bs[buf] + offB[n]);
    #pragma unroll
    for (int m = 0; m < 4; ++m)
      #pragma unroll
      for (int n = 0; n < 4; ++n)
        acc[m][n] = __builtin_amdgcn_mfma_f32_16x16x32_bf16(af[m], bfv[n], acc[m][n], 0, 0, 0);
    __syncthreads();
    buf ^= 1;
  }
  {
    bf16x8 af[4], bfv[4];
    #pragma unroll
    for (int m = 0; m < 4; ++m) af[m] = *(const bf16x8*)((const char*)As[buf] + offA[m]);
    #pragma unroll
    for (int n = 0; n < 4; ++n) bfv[n] = *(const bf16x8*)((const char*)Bs[buf] + offB[n]);
    #pragma unroll
    for (int m = 0; m < 4; ++m)
      #pragma unroll
      for (int n = 0; n < 4; ++n)
        acc[m][n] = __builtin_amdgcn_mfma_f32_16x16x32_bf16(af[m], bfv[n], acc[m][n], 0, 0, 0);
  }

  #pragma unroll
  for (int n = 0; n < 4; ++n) {
    int col = bn + wn * 64 + n * 16 + lq;
    #pragma unroll
    for (int m = 0; m < 4; ++m) {
      #pragma unroll
      for (int r = 0; r < 4; ++r) {
        int row = bm + wm * 64 + m * 16 + quad * 4 + r;
        size_t off = (size_t)row * N + col;
        if (OUT_MODE == 0) Cout[off] = acc[m][n][r];
        else               Cout[off] += acc[m][n][r];
      }
    }
  }
}

// ---------------- causal depthwise conv (K=4) + SiLU ----------------
__global__ __launch_bounds__(256) void conv_kernel(
    const float* __restrict__ xz, const void* __restrict__ cw, size_t cw_off,
    const void* __restrict__ cb, size_t cb_off,
    ushort* __restrict__ xcb, float* __restrict__ xcf,
    const int* __restrict__ flag) {
  int f = *flag;
  int idx = blockIdx.x * 256 + threadIdx.x;           // BLL*DINNER
  int d = idx % DINNER, m = idx / DINNER;
  int l = m & (LSEQ - 1);
  float s = ldf(cb, cb_off + d, f);
  #pragma unroll
  for (int k = 0; k < KCONV; ++k) {
    int ls = l - (KCONV - 1) + k;
    if (ls >= 0)
      s = fmaf(xz[(size_t)(m - (KCONV - 1) + k) * (2 * DINNER) + d],
               ldf(cw, cw_off + d * KCONV + k, f), s);
  }
  float v = s / (1.f + __expf(-s));   // silu
  xcb[idx] = f2bf(v);
  xcf[idx] = v;
}

// ---------------- dt = softplus(dt_raw @ dt_proj_w^T + dt_proj_b) ----------------
__global__ __launch_bounds__(256) void dtproj_kernel(
    const float* __restrict__ dbl, const float* __restrict__ dtwT,
    const void* __restrict__ dtb, size_t dtb_off,
    float* __restrict__ dt, const int* __restrict__ flag) {
  int f = *flag;
  int idx = blockIdx.x * 256 + threadIdx.x;           // BLL*DINNER
  int d = idx % DINNER, m = idx / DINNER;
  const float* rowp = dbl + (size_t)m * 80;
  float s = ldf(dtb, dtb_off + d, f);
  #pragma unroll 8
  for (int r = 0; r < RRANK; ++r)
    s = fmaf(rowp[r], dtwT[(size_t)r * DINNER + d], s);
  dt[idx] = (s > 20.f) ? s : log1pf(__expf(s));
}

// ============ chunk-parallel selective scan, 3-phase (no cross-block sync) ============
// blockIdx = grp*NCHUNK + chunk; grp = b*NDBLK + dblk.
// Thread map: dloc = tid>>2 (one of 64 d), ngrp = tid&3 (4 n-states in registers).
// LDS stages via global_load_lds (linear lane-ordered layouts; wave-uniform base + lane*16).

// P1: chunk-local scan from 0. P computed as exp(sum(dt)*A) — one exp per state.
__global__ __launch_bounds__(256) void scan_p1(
    const float* __restrict__ dt, const float* __restrict__ xcf,
    const float* __restrict__ dbl,
    const void* __restrict__ A_log, size_t al_off,
    float* __restrict__ carryP, float* __restrict__ carryH,
    const int* __restrict__ flag) {
  __shared__ __align__(16) float dt_s[CLEN * DBLK];   // 16 KB
  __shared__ __align__(16) float u_s[CLEN * DBLK];    // 16 KB
  __shared__ __align__(16) f32x4 B4_s[CLEN][4];       // 4 KB

  const int f = *flag;
  const int tid = threadIdx.x;
  const int bid = blockIdx.x;
  const int chunk = bid & (NCHUNK - 1);
  const int grp = bid >> 4;
  const int dblk = grp % NDBLK;
  const int b = grp / NDBLK;
  const int l0 = chunk * CLEN;
  const int dloc = tid >> 2;
  const int ngrp = tid & 3;
  const int d = dblk * DBLK + dloc;

  #pragma unroll
  for (int t = tid; t < CLEN * DBLK / 4; t += 256) {
    int l = t >> 4, c = t & 15;
    size_t off = ((size_t)b * LSEQ + l0 + l) * DINNER + dblk * DBLK + c * 4;
    gload16(dt + off,  (char*)dt_s + (size_t)t * 16);
    gload16(xcf + off, (char*)u_s  + (size_t)t * 16);
  }
  {
    size_t mo = ((size_t)b * LSEQ + l0 + (tid >> 2)) * 80;
    gload16(dbl + mo + 48 + (tid & 3) * 4, (char*)B4_s + (size_t)tid * 16);
  }

  float Ac[4];
  #pragma unroll
  for (int j = 0; j < 4; ++j)
    Ac[j] = -__expf(ldf(A_log, al_off + (size_t)d * NSTATE + ngrp * 4 + j, f));

  __syncthreads();

  float h[4] = {0.f, 0.f, 0.f, 0.f};
  float sdt = 0.f;
  #pragma unroll 4
  for (int l = 0; l < CLEN; ++l) {
    float dtv = dt_s[l * DBLK + dloc], uu = u_s[l * DBLK + dloc];
    f32x4 Bv = B4_s[l][ngrp];
    float dtu = dtv * uu;
    sdt += dtv;
    #pragma unroll
    for (int j = 0; j < 4; ++j) {
      float a = __expf(dtv * Ac[j]);
      h[j] = fmaf(a, h[j], dtu * Bv[j]);
    }
  }
  size_t cb = ((size_t)bid * DBLK + dloc) * NSTATE + ngrp * 4;
  #pragma unroll
  for (int j = 0; j < 4; ++j) {
    carryP[cb + j] = __expf(sdt * Ac[j]);
    carryH[cb + j] = h[j];
  }
}

// P2: sequential carry combine over chunks; coalesced within each group.
__global__ __launch_bounds__(256) void scan_p2(
    const float* __restrict__ carryP, const float* __restrict__ carryH,
    float* __restrict__ hin) {
  int idx = blockIdx.x * 256 + threadIdx.x;          // NGROUPS*DBLK*NSTATE = 49152
  int n = idx & 15;
  int dloc = (idx >> 4) & (DBLK - 1);
  int grp = idx >> 10;
  float h = 0.f;
  for (int c = 0; c < NCHUNK; ++c) {
    size_t ci = (((size_t)(grp * NCHUNK + c)) * DBLK + dloc) * NSTATE + n;
    hin[ci] = h;
    h = fmaf(carryP[ci], h, carryH[ci]);
  }
}

// P3: true recurrence from hin; in-register n-partials, 4-lane reduce,
//     fused D-skip + silu(z) gate, vectorized coalesced bf16 store.
__global__ __launch_bounds__(256) void scan_p3(
    const float* __restrict__ dt, const float* __restrict__ xcf,
    const float* __restrict__ dbl, const float* __restrict__ xz,
    const void* __restrict__ A_log, size_t al_off,
    const void* __restrict__ Dp, size_t dp_off,
    const float* __restrict__ hin, ushort* __restrict__ yg,
    const int* __restrict__ flag) {
  __shared__ __align__(16) float dt_s[CLEN * DBLK];   // 16 KB
  __shared__ __align__(16) float u_s[CLEN * DBLK];    // 16 KB
  __shared__ __align__(16) f32x4 B4_s[CLEN][4];       // 4 KB
  __shared__ __align__(16) f32x4 C4_s[CLEN][4];       // 4 KB
  __shared__ ushort ybuf[CLEN][DBLK];                 // 8 KB  => 48 KB total

  const int f = *flag;
  const int tid = threadIdx.x;
  const int bid = blockIdx.x;
  const int chunk = bid & (NCHUNK - 1);
  const int grp = bid >> 4;
  const int dblk = grp % NDBLK;
  const int b = grp / NDBLK;
  const int l0 = chunk * CLEN;
  const int dloc = tid >> 2;
  const int ngrp = tid & 3;
  const int d = dblk * DBLK + dloc;

  #pragma unroll
  for (int t = tid; t < CLEN * DBLK / 4; t += 256) {
    int l = t >> 4, c = t & 15;
    size_t off = ((size_t)b * LSEQ + l0 + l) * DINNER + dblk * DBLK + c * 4;
    gload16(dt + off,  (char*)dt_s + (size_t)t * 16);
    gload16(xcf + off, (char*)u_s  + (size_t)t * 16);
  }
  {
    size_t mo = ((size_t)b * LSEQ + l0 + (tid >> 2)) * 80;
    gload16(dbl + mo + 48 + (tid & 3) * 4, (char*)B4_s + (size_t)tid * 16);
    gload16(dbl + mo + 64 + (tid & 3) * 4, (char*)C4_s + (size_t)tid * 16);
  }

  float Ac[4];
  #pragma unroll
  for (int j = 0; j < 4; ++j)
    Ac[j] = -__expf(ldf(A_log, al_off + (size_t)d * NSTATE + ngrp * 4 + j, f));
  const float Dd = ldf(Dp, dp_off + d, f);

  size_t hb = ((size_t)bid * DBLK + dloc) * NSTATE + ngrp * 4;
  float hp[4] = {hin[hb], hin[hb + 1], hin[hb + 2], hin[hb + 3]};

  __syncthreads();

  #pragma unroll 4
  for (int l = 0; l < CLEN; ++l) {
    float dtv = dt_s[l * DBLK + dloc], uu = u_s[l * DBLK + dloc];
    f32x4 Bv = B4_s[l][ngrp];
    f32x4 Cv = C4_s[l][ngrp];
    float dtu = dtv * uu;
    float yp = 0.f;
    #pragma unroll
    for (int j = 0; j < 4; ++j) {
      float a = __expf(dtv * Ac[j]);
      hp[j] = fmaf(a, hp[j], dtu * Bv[j]);
      yp = fmaf(hp[j], Cv[j], yp);
    }
    yp += __shfl_xor(yp, 1, 64);
    yp += __shfl_xor(yp, 2, 64);
    if (ngrp == 0) ybuf[l][dloc] = f2bf(yp + uu * Dd);
  }
  __syncthreads();

  // ---- gated write: y * silu(z), coalesced vectorized ----
  #pragma unroll
  for (int t = tid; t < CLEN * DBLK / 4; t += 256) {
    int l = t >> 4, c = t & 15;
    size_t m = (size_t)b * LSEQ + l0 + l;
    f32x4 z4 = *(const f32x4*)(xz + m * (2 * DINNER) + DINNER + dblk * DBLK + c * 4);
    u16x4 o;
    #pragma unroll
    for (int j = 0; j < 4; ++j) {
      float y = bf2f(ybuf[l][c * 4 + j]);
      float zv = z4[j];
      float g = zv / (1.f + __expf(-zv));
      o[j] = f2bf(y * g);
    }
    *(u16x4*)(yg + m * DINNER + dblk * DBLK + c * 4) = o;
  }
}

extern "C" void kernel_launch(void* const* d_in, const int* in_sizes, int n_in,
                              void* d_out, int out_size, void* d_ws, size_t ws_size,
                              hipStream_t stream) {
  const int*  ids   = (const int*)d_in[0];
  const void* emb   = d_in[1];
  const void* inw   = d_in[2];
  const void* cw    = d_in[3];
  const void* cb    = d_in[4];
  const void* xpw   = d_in[5];
  const void* dtw   = d_in[6];
  const void* dtb   = d_in[7];
  const void* alog  = d_in[8];
  const void* dpar  = d_in[9];
  const void* outw  = d_in[10];
  const void* normw = d_in[11];
  const void* normf = d_in[12];

  // workspace layout, all chunks 16B-aligned
  char* p = (char*)d_ws;
  int*    flag = (int*)p;    p += 16;
  float*  res  = (float*)p;  p += (size_t)BLL * DMODEL * 4;
  ushort* h    = (ushort*)p; p += (size_t)BLL * DMODEL * 2;
  float*  xz   = (float*)p;  p += (size_t)BLL * 2 * DINNER * 4;
  ushort* xcb  = (ushort*)p; p += (size_t)BLL * DINNER * 2;
  float*  xcf  = (float*)p;  p += (size_t)BLL * DINNER * 4;
  float*  dbl  = (float*)p;  p += (size_t)BLL * 80 * 4;
  float*  dt   = (float*)p;  p += (size_t)BLL * DINNER * 4;
  ushort* yg   = (ushort*)p; p += (size_t)BLL * DINNER * 2;
  float*  carryP = (float*)p; p += (size_t)SCAN_GRID * DBLK * NSTATE * 4;
  float*  carryH = (float*)p; p += (size_t)SCAN_GRID * DBLK * NSTATE * 4;
  float*  hin    = (float*)p; p += (size_t)SCAN_GRID * DBLK * NSTATE * 4;
  float*  dtwT = (float*)p;  p += (size_t)NLAYER * RRANK * DINNER * 4;
  ushort* inwb = (ushort*)p; p += (size_t)NLAYER * 2 * DINNER * DMODEL * 2;
  ushort* xpwb = (ushort*)p; p += (size_t)NLAYER * 80 * DINNER * 2;
  ushort* outwb= (ushort*)p; p += (size_t)NLAYER * DMODEL * DINNER * 2;

  probe_kernel<<<1, 256, 0, stream>>>(emb, flag);
  wcvt_kernel<<<(NLAYER * 2 * DINNER * DMODEL) / 256, 256, 0, stream>>>(inw, 0, inwb, flag);
  wcvt_kernel<<<(NLAYER * 80 * DINNER) / 256, 256, 0, stream>>>(xpw, 0, xpwb, flag);
  wcvt_kernel<<<(NLAYER * DMODEL * DINNER) / 256, 256, 0, stream>>>(outw, 0, outwb, flag);
  dtwT_kernel<<<(NLAYER * RRANK * DINNER) / 256, 256, 0, stream>>>(dtw, dtwT, flag);

  embed_kernel<<<BLL * DMODEL / 256, 256, 0, stream>>>(ids, emb, res, flag);

  for (int i = 0; i < NLAYER; ++i) {
    rms_kernel<<<BLL, 256, 0, stream>>>(res, normw, (size_t)i * DMODEL, h, flag, 0);
    gemm128<0><<<dim3(2 * DINNER / GBN, BLL / GBM), 256, 0, stream>>>(
        h, inwb + (size_t)i * 2 * DINNER * DMODEL, xz, BLL, 2 * DINNER, DMODEL);
    conv_kernel<<<BLL * DINNER / 256, 256, 0, stream>>>(
        xz, cw, (size_t)i * DINNER * KCONV, cb, (size_t)i * DINNER, xcb, xcf, flag);
    gemm_nt<0><<<dim3(2, BLL / 64), 256, 0, stream>>>(
        xcb, xpwb + (size_t)i * 80 * DINNER, dbl, BLL, 80, DINNER);
    dtproj_kernel<<<BLL * DINNER / 256, 256, 0, stream>>>(
        dbl, dtwT + (size_t)i * RRANK * DINNER, dtb, (size_t)i * DINNER, dt, flag);
    scan_p1<<<SCAN_GRID, 256, 0, stream>>>(
        dt, xcf, dbl, alog, (size_t)i * DINNER * NSTATE, carryP, carryH, flag);
    scan_p2<<<NGROUPS * DBLK * NSTATE / 256, 256, 0, stream>>>(carryP, carryH, hin);
    scan_p3<<<SCAN_GRID, 256, 0, stream>>>(
        dt, xcf, dbl, xz, alog, (size_t)i * DINNER * NSTATE, dpar, (size_t)i * DINNER,
        hin, yg, flag);
    gemm128<2><<<dim3(DMODEL / GBN, BLL / GBM), 256, 0, stream>>>(
        yg, outwb + (size_t)i * DMODEL * DINNER, res, BLL, DMODEL, DINNER);
  }

  rms_kernel<<<BLL, 256, 0, stream>>>(res, normf, 0, d_out, flag, 1);
}

// Round 7
// 1706.847 us; speedup vs baseline: 1.3899x; 1.2613x over previous
//
#include <hip/hip_runtime.h>
#include <stdint.h>

#define DMODEL 768
#define DINNER 1536
#define NSTATE 16
#define KCONV 4
#define RRANK 48
#define NLAYER 8
#define BLL 2048   // B*L tokens
#define LSEQ 1024
#define BATCH 2
#define NCHUNK 16
#define CLEN 64    // LSEQ / NCHUNK
#define DBLK 64
#define NDBLK (DINNER / DBLK)        // 24
#define NGROUPS (BATCH * NDBLK)      // 48
#define SCAN_GRID (NGROUPS * NCHUNK) // 768

#define GBM 128
#define GBN 128
#define GBK 32

__device__ __forceinline__ float bf2f(ushort u) {
  union { float f; uint32_t i; } v; v.i = ((uint32_t)u) << 16; return v.f;
}
__device__ __forceinline__ ushort f2bf(float f) {
  uint32_t x = __float_as_uint(f);
  uint32_t r = (x + 0x7fffu + ((x >> 16) & 1u)) >> 16;  // round-nearest-even
  return (ushort)r;
}
// flag-switched input loader: fp32flag=1 -> fp32 data, 0 -> bf16 data
__device__ __forceinline__ float ldf(const void* p, size_t i, int fp32flag) {
  return fp32flag ? ((const float*)p)[i] : bf2f(((const ushort*)p)[i]);
}

typedef __attribute__((ext_vector_type(8))) __bf16 bf16x8;
typedef __attribute__((ext_vector_type(4))) float f32x4;
typedef __attribute__((ext_vector_type(4))) unsigned short u16x4;

typedef __attribute__((address_space(3))) unsigned int lds_u32_t;
typedef const __attribute__((address_space(1))) unsigned int glb_u32_t;
// async global->LDS, 16B per lane; LDS dest = wave-uniform base + lane*16
__device__ __forceinline__ void gload16(const void* g, void* l) {
  __builtin_amdgcn_global_load_lds((glb_u32_t*)g, (lds_u32_t*)l, 16, 0, 0);
}

// ---------------- dtype probe: is input data fp32 or bf16? ----------------
__global__ __launch_bounds__(256) void probe_kernel(const void* emb, int* flag) {
  int tid = threadIdx.x;
  int good = 0;
  for (int i = tid; i < 4096; i += 256) {
    float v = bf2f(((const ushort*)emb)[2 * i]);  // little-endian low half
    float a = fabsf(v);
    if (v == 0.f || (a >= 1e-8f && a <= 1e4f)) good++;
  }
  __shared__ int red[4];
  #pragma unroll
  for (int off = 32; off > 0; off >>= 1) good += __shfl_down(good, off, 64);
  if ((tid & 63) == 0) red[tid >> 6] = good;
  __syncthreads();
  if (tid == 0) {
    int g = red[0] + red[1] + red[2] + red[3];
    *flag = (g < 2867) ? 1 : 0;   // <70% sane => fp32 inputs
  }
}

// ---------------- weight convert: input (either dtype) -> bf16 ws copy ----------------
__global__ __launch_bounds__(256) void wcvt_kernel(const void* src, size_t elem_off,
                                                   ushort* __restrict__ dst,
                                                   const int* __restrict__ flag) {
  int f = *flag;
  size_t i = (size_t)blockIdx.x * 256 + threadIdx.x;
  dst[i] = f2bf(ldf(src, elem_off + i, f));
}

// ---------------- dt_proj_w transpose: [l][d][r] -> [l][r][d], fp32 ----------------
__global__ __launch_bounds__(256) void dtwT_kernel(const void* dtw, float* __restrict__ dtwT,
                                                   const int* __restrict__ flag) {
  int f = *flag;
  size_t i = (size_t)blockIdx.x * 256 + threadIdx.x;   // NLAYER*RRANK*DINNER
  int d = i % DINNER;
  int r = (i / DINNER) % RRANK;
  int l = i / (DINNER * RRANK);
  dtwT[i] = ldf(dtw, ((size_t)l * DINNER + d) * RRANK + r, f);
}

// ---------------- embedding lookup -> fp32 residual ----------------
__global__ __launch_bounds__(256) void embed_kernel(
    const int* __restrict__ ids, const void* __restrict__ emb,
    float* __restrict__ res, const int* __restrict__ flag) {
  int f = *flag;
  int idx = blockIdx.x * 256 + threadIdx.x;           // BLL*DMODEL
  int m = idx / DMODEL, c = idx % DMODEL;
  res[idx] = ldf(emb, (size_t)ids[m] * DMODEL + c, f);
}

// ---------------- RMSNorm with fused residual add of split-K out_proj partials ----------
// do_add: res += oadd[slice0] + oadd[slice1] (written back); then rms-normalize.
__global__ __launch_bounds__(256) void rms_kernel(
    float* __restrict__ res, const float* __restrict__ oadd,
    const void* __restrict__ w, size_t w_off,
    void* __restrict__ out, const int* __restrict__ flag,
    int final_store, int do_add) {
  int f = *flag;
  int m = blockIdx.x;
  float* r = res + (size_t)m * DMODEL;
  float v[3];                                          // DMODEL = 3*256
  float ss = 0.f;
  #pragma unroll
  for (int t = 0; t < 3; ++t) {
    int i = threadIdx.x + t * 256;
    float x = r[i];
    if (do_add) {
      x += oadd[(size_t)m * DMODEL + i] + oadd[((size_t)BLL + m) * DMODEL + i];
      r[i] = x;
    }
    v[t] = x;
    ss += x * x;
  }
  #pragma unroll
  for (int off = 32; off > 0; off >>= 1) ss += __shfl_down(ss, off, 64);
  __shared__ float red[4];
  if ((threadIdx.x & 63) == 0) red[threadIdx.x >> 6] = ss;
  __syncthreads();
  float scale = rsqrtf((red[0] + red[1] + red[2] + red[3]) / (float)DMODEL + 1e-5f);
  #pragma unroll
  for (int t = 0; t < 3; ++t) {
    int i = threadIdx.x + t * 256;
    float o = v[t] * scale * ldf(w, w_off + i, f);
    size_t off = (size_t)m * DMODEL + i;
    if (final_store) {
      if (f) ((float*)out)[off] = o; else ((ushort*)out)[off] = f2bf(o);
    } else {
      ((ushort*)out)[off] = f2bf(o);
    }
  }
}

// ---------------- small GEMM w/ split-K atomics: C[M,N] += A[M,K]*W[N,K]^T ----------------
// grid.z = ksplit; C must be zeroed beforehand.
__global__ __launch_bounds__(256) void gemm_nt_sk(
    const ushort* __restrict__ A, const ushort* __restrict__ W,
    float* __restrict__ Cout, int M, int N, int K) {
  int wave = threadIdx.x >> 6, lane = threadIdx.x & 63;
  int quad = lane >> 4, lq = lane & 15;
  int bm = blockIdx.y * 64, bn = blockIdx.x * 64;
  const int kslice = K / gridDim.z;
  const int kbase = blockIdx.z * kslice;
  int row = bm + wave * 16 + lq;
  const ushort* Ap = A + (size_t)row * K + kbase + quad * 8;
  f32x4 acc[4] = {};
  for (int kk = 0; kk < kslice; kk += 32) {
    bf16x8 af = *(const bf16x8*)(Ap + kk);
    #pragma unroll
    for (int t = 0; t < 4; ++t) {
      int col = bn + t * 16 + lq;
      bf16x8 bfv = {};
      if (col < N) bfv = *(const bf16x8*)(W + (size_t)col * K + kbase + kk + quad * 8);
      acc[t] = __builtin_amdgcn_mfma_f32_16x16x32_bf16(af, bfv, acc[t], 0, 0, 0);
    }
  }
  #pragma unroll
  for (int t = 0; t < 4; ++t) {
    int col = bn + t * 16 + lq;
    if (col >= N) continue;
    #pragma unroll
    for (int r = 0; r < 4; ++r) {
      int rr = bm + wave * 16 + quad * 4 + r;
      atomicAdd(&Cout[(size_t)rr * N + col], acc[t][r]);
    }
  }
}

// ---------------- 128x128 LDS-staged MFMA GEMM (m97 structure) ----------------
// Requires M%128==0, N%128==0, K%(32*gridDim.z)==0, (gx*gy)%8==0 (XCD swizzle).
// grid.z = ksplit; slice z stores to Cout + z*M*N (partial buffers; z=1 -> plain store).
// LDS tiles [128][32] bf16, linear dest for global_load_lds; bank-conflict fix via
// both-sides XOR swizzle: 16B-chunk index ^= (row>>1)&3 (involution; rule 21).
__global__ __launch_bounds__(256) void gemm128(
    const ushort* __restrict__ A, const ushort* __restrict__ W,
    float* __restrict__ Cout, int M, int N, int K) {
  __shared__ __align__(16) ushort As[2][GBM * GBK];   // 8 KB each
  __shared__ __align__(16) ushort Bs[2][GBM * GBK];
  const int tid = threadIdx.x;
  const int wid = tid >> 6, lane = tid & 63;
  const int quad = lane >> 4, lq = lane & 15;
  const int wm = wid >> 1, wn = wid & 1;              // 2x2 waves, 64x64 each

  // XCD-aware bijective swizzle of the flattened xy block index
  const int nwg = gridDim.x * gridDim.y;
  const int orig = blockIdx.y * gridDim.x + blockIdx.x;
  const int swz = (orig & 7) * (nwg >> 3) + (orig >> 3);
  const int bx = swz % gridDim.x, by = swz / gridDim.x;
  const int bm = by * GBM, bn = bx * GBN;

  const int kslice = K / gridDim.z;
  const int kbase = blockIdx.z * kslice;
  float* Cp = Cout + (size_t)blockIdx.z * M * N;

  // staging: 512 chunks of 16B per tile; chunk i -> LDS offset i*16 (linear).
  // physical chunk (row, pc) holds logical k-octet lc = pc ^ ((row>>1)&3).
  const int c0 = tid, c1 = tid + 256;
  const int r0 = c0 >> 2, lc0 = (c0 & 3) ^ ((r0 >> 1) & 3);
  const int r1 = c1 >> 2, lc1 = (c1 & 3) ^ ((r1 >> 1) & 3);
  const ushort* Ag0 = A + (size_t)(bm + r0) * K + kbase + lc0 * 8;
  const ushort* Ag1 = A + (size_t)(bm + r1) * K + kbase + lc1 * 8;
  const ushort* Bg0 = W + (size_t)(bn + r0) * K + kbase + lc0 * 8;
  const ushort* Bg1 = W + (size_t)(bn + r1) * K + kbase + lc1 * 8;
  const int ls0 = wid * 512;                          // elem offsets (wave-uniform)
  const int ls1 = 2048 + wid * 512;

  // per-lane ds_read byte offsets (swizzled)
  int offA[4], offB[4];
  #pragma unroll
  for (int m = 0; m < 4; ++m) {
    int ra = wm * 64 + m * 16 + lq;
    offA[m] = ra * 64 + ((quad ^ ((ra >> 1) & 3)) << 4);
    int rb = wn * 64 + m * 16 + lq;
    offB[m] = rb * 64 + ((quad ^ ((rb >> 1) & 3)) << 4);
  }

  f32x4 acc[4][4] = {};
  const int nk = kslice >> 5;

  gload16(Ag0, &As[0][ls0]); gload16(Ag1, &As[0][ls1]);
  gload16(Bg0, &Bs[0][ls0]); gload16(Bg1, &Bs[0][ls1]);
  __syncthreads();

  int buf = 0;
  for (int kk = 1; kk < nk; ++kk) {
    const int ko = kk << 5;
    gload16(Ag0 + ko, &As[buf ^ 1][ls0]); gload16(Ag1 + ko, &As[buf ^ 1][ls1]);
    gload16(Bg0 + ko, &Bs[buf ^ 1][ls0]); gload16(Bg1 + ko, &Bs[buf ^ 1][ls1]);
    bf16x8 af[4], bfv[4];
    #pragma unroll
    for (int m = 0; m < 4; ++m) af[m] = *(const bf16x8*)((const char*)As[buf] + offA[m]);
    #pragma unroll
    for (int n = 0; n < 4; ++n) bfv[n] = *(const bf16x8*)((const char*)Bs[buf] + offB[n]);
    #pragma unroll
    for (int m = 0; m < 4; ++m)
      #pragma unroll
      for (int n = 0; n < 4; ++n)
        acc[m][n] = __builtin_amdgcn_mfma_f32_16x16x32_bf16(af[m], bfv[n], acc[m][n], 0, 0, 0);
    __syncthreads();
    buf ^= 1;
  }
  {
    bf16x8 af[4], bfv[4];
    #pragma unroll
    for (int m = 0; m < 4; ++m) af[m] = *(const bf16x8*)((const char*)As[buf] + offA[m]);
    #pragma unroll
    for (int n = 0; n < 4; ++n) bfv[n] = *(const bf16x8*)((const char*)Bs[buf] + offB[n]);
    #pragma unroll
    for (int m = 0; m < 4; ++m)
      #pragma unroll
      for (int n = 0; n < 4; ++n)
        acc[m][n] = __builtin_amdgcn_mfma_f32_16x16x32_bf16(af[m], bfv[n], acc[m][n], 0, 0, 0);
  }

  #pragma unroll
  for (int n = 0; n < 4; ++n) {
    int col = bn + wn * 64 + n * 16 + lq;
    #pragma unroll
    for (int m = 0; m < 4; ++m) {
      #pragma unroll
      for (int r = 0; r < 4; ++r) {
        int row = bm + wm * 64 + m * 16 + quad * 4 + r;
        Cp[(size_t)row * N + col] = acc[m][n][r];
      }
    }
  }
}

// ---------------- causal depthwise conv (K=4) + SiLU; also zero-inits dbl ----------------
__global__ __launch_bounds__(256) void conv_kernel(
    const float* __restrict__ xz, const void* __restrict__ cw, size_t cw_off,
    const void* __restrict__ cb, size_t cb_off,
    ushort* __restrict__ xcb, float* __restrict__ xcf, float* __restrict__ dbl,
    const int* __restrict__ flag) {
  int f = *flag;
  int idx = blockIdx.x * 256 + threadIdx.x;           // BLL*DINNER
  if (idx < BLL * 80) dbl[idx] = 0.f;                 // zero for split-K atomics
  int d = idx % DINNER, m = idx / DINNER;
  int l = m & (LSEQ - 1);
  float s = ldf(cb, cb_off + d, f);
  #pragma unroll
  for (int k = 0; k < KCONV; ++k) {
    int ls = l - (KCONV - 1) + k;
    if (ls >= 0)
      s = fmaf(xz[(size_t)(m - (KCONV - 1) + k) * (2 * DINNER) + d],
               ldf(cw, cw_off + d * KCONV + k, f), s);
  }
  float v = s / (1.f + __expf(-s));   // silu
  xcb[idx] = f2bf(v);
  xcf[idx] = v;
}

// ---------------- dt = softplus(dt_raw @ dt_proj_w^T + dt_proj_b) ----------------
__global__ __launch_bounds__(256) void dtproj_kernel(
    const float* __restrict__ dbl, const float* __restrict__ dtwT,
    const void* __restrict__ dtb, size_t dtb_off,
    float* __restrict__ dt, const int* __restrict__ flag) {
  int f = *flag;
  int idx = blockIdx.x * 256 + threadIdx.x;           // BLL*DINNER
  int d = idx % DINNER, m = idx / DINNER;
  const float* rowp = dbl + (size_t)m * 80;
  float s = ldf(dtb, dtb_off + d, f);
  #pragma unroll 8
  for (int r = 0; r < RRANK; ++r)
    s = fmaf(rowp[r], dtwT[(size_t)r * DINNER + d], s);
  dt[idx] = (s > 20.f) ? s : __logf(1.f + __expf(s));  // HW transcendentals only
}

// ============ chunk-parallel selective scan, 3-phase (no cross-block sync) ============
// blockIdx = grp*NCHUNK + chunk; grp = b*NDBLK + dblk.
// Thread map: dloc = tid>>2 (one of 64 d), ngrp = tid&3 (4 n-states in registers).
// LDS stages via global_load_lds (linear lane-ordered layouts; wave-uniform base + lane*16).

// P1: chunk-local scan from 0. P computed as exp(sum(dt)*A) — one exp per state.
__global__ __launch_bounds__(256) void scan_p1(
    const float* __restrict__ dt, const float* __restrict__ xcf,
    const float* __restrict__ dbl,
    const void* __restrict__ A_log, size_t al_off,
    float* __restrict__ carryP, float* __restrict__ carryH,
    const int* __restrict__ flag) {
  __shared__ __align__(16) float dt_s[CLEN * DBLK];   // 16 KB
  __shared__ __align__(16) float u_s[CLEN * DBLK];    // 16 KB
  __shared__ __align__(16) f32x4 B4_s[CLEN][4];       // 4 KB

  const int f = *flag;
  const int tid = threadIdx.x;
  const int bid = blockIdx.x;
  const int chunk = bid & (NCHUNK - 1);
  const int grp = bid >> 4;
  const int dblk = grp % NDBLK;
  const int b = grp / NDBLK;
  const int l0 = chunk * CLEN;
  const int dloc = tid >> 2;
  const int ngrp = tid & 3;
  const int d = dblk * DBLK + dloc;

  #pragma unroll
  for (int t = tid; t < CLEN * DBLK / 4; t += 256) {
    int l = t >> 4, c = t & 15;
    size_t off = ((size_t)b * LSEQ + l0 + l) * DINNER + dblk * DBLK + c * 4;
    gload16(dt + off,  (char*)dt_s + (size_t)t * 16);
    gload16(xcf + off, (char*)u_s  + (size_t)t * 16);
  }
  {
    size_t mo = ((size_t)b * LSEQ + l0 + (tid >> 2)) * 80;
    gload16(dbl + mo + 48 + (tid & 3) * 4, (char*)B4_s + (size_t)tid * 16);
  }

  float Ac[4];
  #pragma unroll
  for (int j = 0; j < 4; ++j)
    Ac[j] = -__expf(ldf(A_log, al_off + (size_t)d * NSTATE + ngrp * 4 + j, f));

  __syncthreads();

  float h[4] = {0.f, 0.f, 0.f, 0.f};
  float sdt = 0.f;
  #pragma unroll 4
  for (int l = 0; l < CLEN; ++l) {
    float dtv = dt_s[l * DBLK + dloc], uu = u_s[l * DBLK + dloc];
    f32x4 Bv = B4_s[l][ngrp];
    float dtu = dtv * uu;
    sdt += dtv;
    #pragma unroll
    for (int j = 0; j < 4; ++j) {
      float a = __expf(dtv * Ac[j]);
      h[j] = fmaf(a, h[j], dtu * Bv[j]);
    }
  }
  size_t cb = ((size_t)bid * DBLK + dloc) * NSTATE + ngrp * 4;
  #pragma unroll
  for (int j = 0; j < 4; ++j) {
    carryP[cb + j] = __expf(sdt * Ac[j]);
    carryH[cb + j] = h[j];
  }
}

// P2: sequential carry combine over chunks; coalesced within each group.
__global__ __launch_bounds__(256) void scan_p2(
    const float* __restrict__ carryP, const float* __restrict__ carryH,
    float* __restrict__ hin) {
  int idx = blockIdx.x * 256 + threadIdx.x;          // NGROUPS*DBLK*NSTATE = 49152
  int n = idx & 15;
  int dloc = (idx >> 4) & (DBLK - 1);
  int grp = idx >> 10;
  float h = 0.f;
  for (int c = 0; c < NCHUNK; ++c) {
    size_t ci = (((size_t)(grp * NCHUNK + c)) * DBLK + dloc) * NSTATE + n;
    hin[ci] = h;
    h = fmaf(carryP[ci], h, carryH[ci]);
  }
}

// P3: true recurrence from hin; in-register n-partials, 4-lane reduce,
//     fused D-skip + silu(z) gate, vectorized coalesced bf16 store.
__global__ __launch_bounds__(256) void scan_p3(
    const float* __restrict__ dt, const float* __restrict__ xcf,
    const float* __restrict__ dbl, const float* __restrict__ xz,
    const void* __restrict__ A_log, size_t al_off,
    const void* __restrict__ Dp, size_t dp_off,
    const float* __restrict__ hin, ushort* __restrict__ yg,
    const int* __restrict__ flag) {
  __shared__ __align__(16) float dt_s[CLEN * DBLK];   // 16 KB
  __shared__ __align__(16) float u_s[CLEN * DBLK];    // 16 KB
  __shared__ __align__(16) f32x4 B4_s[CLEN][4];       // 4 KB
  __shared__ __align__(16) f32x4 C4_s[CLEN][4];       // 4 KB
  __shared__ ushort ybuf[CLEN][DBLK];                 // 8 KB  => 48 KB total

  const int f = *flag;
  const int tid = threadIdx.x;
  const int bid = blockIdx.x;
  const int chunk = bid & (NCHUNK - 1);
  const int grp = bid >> 4;
  const int dblk = grp % NDBLK;
  const int b = grp / NDBLK;
  const int l0 = chunk * CLEN;
  const int dloc = tid >> 2;
  const int ngrp = tid & 3;
  const int d = dblk * DBLK + dloc;

  #pragma unroll
  for (int t = tid; t < CLEN * DBLK / 4; t += 256) {
    int l = t >> 4, c = t & 15;
    size_t off = ((size_t)b * LSEQ + l0 + l) * DINNER + dblk * DBLK + c * 4;
    gload16(dt + off,  (char*)dt_s + (size_t)t * 16);
    gload16(xcf + off, (char*)u_s  + (size_t)t * 16);
  }
  {
    size_t mo = ((size_t)b * LSEQ + l0 + (tid >> 2)) * 80;
    gload16(dbl + mo + 48 + (tid & 3) * 4, (char*)B4_s + (size_t)tid * 16);
    gload16(dbl + mo + 64 + (tid & 3) * 4, (char*)C4_s + (size_t)tid * 16);
  }

  float Ac[4];
  #pragma unroll
  for (int j = 0; j < 4; ++j)
    Ac[j] = -__expf(ldf(A_log, al_off + (size_t)d * NSTATE + ngrp * 4 + j, f));
  const float Dd = ldf(Dp, dp_off + d, f);

  size_t hb = ((size_t)bid * DBLK + dloc) * NSTATE + ngrp * 4;
  float hp[4] = {hin[hb], hin[hb + 1], hin[hb + 2], hin[hb + 3]};

  __syncthreads();

  #pragma unroll 4
  for (int l = 0; l < CLEN; ++l) {
    float dtv = dt_s[l * DBLK + dloc], uu = u_s[l * DBLK + dloc];
    f32x4 Bv = B4_s[l][ngrp];
    f32x4 Cv = C4_s[l][ngrp];
    float dtu = dtv * uu;
    float yp = 0.f;
    #pragma unroll
    for (int j = 0; j < 4; ++j) {
      float a = __expf(dtv * Ac[j]);
      hp[j] = fmaf(a, hp[j], dtu * Bv[j]);
      yp = fmaf(hp[j], Cv[j], yp);
    }
    yp += __shfl_xor(yp, 1, 64);
    yp += __shfl_xor(yp, 2, 64);
    if (ngrp == 0) ybuf[l][dloc] = f2bf(yp + uu * Dd);
  }
  __syncthreads();

  // ---- gated write: y * silu(z), coalesced vectorized ----
  #pragma unroll
  for (int t = tid; t < CLEN * DBLK / 4; t += 256) {
    int l = t >> 4, c = t & 15;
    size_t m = (size_t)b * LSEQ + l0 + l;
    f32x4 z4 = *(const f32x4*)(xz + m * (2 * DINNER) + DINNER + dblk * DBLK + c * 4);
    u16x4 o;
    #pragma unroll
    for (int j = 0; j < 4; ++j) {
      float y = bf2f(ybuf[l][c * 4 + j]);
      float zv = z4[j];
      float g = zv / (1.f + __expf(-zv));
      o[j] = f2bf(y * g);
    }
    *(u16x4*)(yg + m * DINNER + dblk * DBLK + c * 4) = o;
  }
}

extern "C" void kernel_launch(void* const* d_in, const int* in_sizes, int n_in,
                              void* d_out, int out_size, void* d_ws, size_t ws_size,
                              hipStream_t stream) {
  const int*  ids   = (const int*)d_in[0];
  const void* emb   = d_in[1];
  const void* inw   = d_in[2];
  const void* cw    = d_in[3];
  const void* cb    = d_in[4];
  const void* xpw   = d_in[5];
  const void* dtw   = d_in[6];
  const void* dtb   = d_in[7];
  const void* alog  = d_in[8];
  const void* dpar  = d_in[9];
  const void* outw  = d_in[10];
  const void* normw = d_in[11];
  const void* normf = d_in[12];

  // workspace layout, all chunks 16B-aligned
  char* p = (char*)d_ws;
  int*    flag = (int*)p;    p += 16;
  float*  res  = (float*)p;  p += (size_t)BLL * DMODEL * 4;
  ushort* h    = (ushort*)p; p += (size_t)BLL * DMODEL * 2;
  float*  xz   = (float*)p;  p += (size_t)BLL * 2 * DINNER * 4;
  ushort* xcb  = (ushort*)p; p += (size_t)BLL * DINNER * 2;
  float*  xcf  = (float*)p;  p += (size_t)BLL * DINNER * 4;
  float*  dbl  = (float*)p;  p += (size_t)BLL * 80 * 4;
  float*  dt   = (float*)p;  p += (size_t)BLL * DINNER * 4;
  ushort* yg   = (ushort*)p; p += (size_t)BLL * DINNER * 2;
  float*  obuf = (float*)p;  p += (size_t)2 * BLL * DMODEL * 4;   // split-K partials
  float*  carryP = (float*)p; p += (size_t)SCAN_GRID * DBLK * NSTATE * 4;
  float*  carryH = (float*)p; p += (size_t)SCAN_GRID * DBLK * NSTATE * 4;
  float*  hin    = (float*)p; p += (size_t)SCAN_GRID * DBLK * NSTATE * 4;
  float*  dtwT = (float*)p;  p += (size_t)NLAYER * RRANK * DINNER * 4;
  ushort* inwb = (ushort*)p; p += (size_t)NLAYER * 2 * DINNER * DMODEL * 2;
  ushort* xpwb = (ushort*)p; p += (size_t)NLAYER * 80 * DINNER * 2;
  ushort* outwb= (ushort*)p; p += (size_t)NLAYER * DMODEL * DINNER * 2;

  probe_kernel<<<1, 256, 0, stream>>>(emb, flag);
  wcvt_kernel<<<(NLAYER * 2 * DINNER * DMODEL) / 256, 256, 0, stream>>>(inw, 0, inwb, flag);
  wcvt_kernel<<<(NLAYER * 80 * DINNER) / 256, 256, 0, stream>>>(xpw, 0, xpwb, flag);
  wcvt_kernel<<<(NLAYER * DMODEL * DINNER) / 256, 256, 0, stream>>>(outw, 0, outwb, flag);
  dtwT_kernel<<<(NLAYER * RRANK * DINNER) / 256, 256, 0, stream>>>(dtw, dtwT, flag);

  embed_kernel<<<BLL * DMODEL / 256, 256, 0, stream>>>(ids, emb, res, flag);

  for (int i = 0; i < NLAYER; ++i) {
    rms_kernel<<<BLL, 256, 0, stream>>>(res, obuf, normw, (size_t)i * DMODEL,
                                        h, flag, 0, i > 0);
    gemm128<<<dim3(2 * DINNER / GBN, BLL / GBM), 256, 0, stream>>>(
        h, inwb + (size_t)i * 2 * DINNER * DMODEL, xz, BLL, 2 * DINNER, DMODEL);
    conv_kernel<<<BLL * DINNER / 256, 256, 0, stream>>>(
        xz, cw, (size_t)i * DINNER * KCONV, cb, (size_t)i * DINNER, xcb, xcf, dbl, flag);
    gemm_nt_sk<<<dim3(2, BLL / 64, 4), 256, 0, stream>>>(
        xcb, xpwb + (size_t)i * 80 * DINNER, dbl, BLL, 80, DINNER);
    dtproj_kernel<<<BLL * DINNER / 256, 256, 0, stream>>>(
        dbl, dtwT + (size_t)i * RRANK * DINNER, dtb, (size_t)i * DINNER, dt, flag);
    scan_p1<<<SCAN_GRID, 256, 0, stream>>>(
        dt, xcf, dbl, alog, (size_t)i * DINNER * NSTATE, carryP, carryH, flag);
    scan_p2<<<NGROUPS * DBLK * NSTATE / 256, 256, 0, stream>>>(carryP, carryH, hin);
    scan_p3<<<SCAN_GRID, 256, 0, stream>>>(
        dt, xcf, dbl, xz, alog, (size_t)i * DINNER * NSTATE, dpar, (size_t)i * DINNER,
        hin, yg, flag);
    gemm128<<<dim3(DMODEL / GBN, BLL / GBM, 2), 256, 0, stream>>>(
        yg, outwb + (size_t)i * DMODEL * DINNER, obuf, BLL, DMODEL, DINNER);
  }

  rms_kernel<<<BLL, 256, 0, stream>>>(res, obuf, normf, 0, d_out, flag, 1, 1);
}